// Round 1
// baseline (412.554 us; speedup 1.0000x reference)
//
#include <hip/hip_runtime.h>
#include <hip/hip_bf16.h>

#define HID 128

// ---------------- CSR build (by dst) ----------------
__global__ void k_count(const int* __restrict__ dstv, int* __restrict__ deg, int E) {
  int e = blockIdx.x * 256 + threadIdx.x;
  if (e < E) atomicAdd(&deg[dstv[e]], 1);
}

__global__ __launch_bounds__(256) void k_scan1(const int* __restrict__ deg, int* __restrict__ inc,
                                               int* __restrict__ bsum, int N) {
  __shared__ int s[256];
  int i = blockIdx.x * 256 + threadIdx.x;
  int v = (i < N) ? deg[i] : 0;
  s[threadIdx.x] = v;
  __syncthreads();
  #pragma unroll
  for (int off = 1; off < 256; off <<= 1) {
    int t = (threadIdx.x >= off) ? s[threadIdx.x - off] : 0;
    __syncthreads();
    s[threadIdx.x] += t;
    __syncthreads();
  }
  if (i < N) inc[i] = s[threadIdx.x];
  if (threadIdx.x == 255) bsum[blockIdx.x] = s[255];
}

__global__ __launch_bounds__(256) void k_scan2(int* __restrict__ bsum, int nb) {
  __shared__ int s[256];
  int v = (threadIdx.x < nb) ? bsum[threadIdx.x] : 0;
  s[threadIdx.x] = v;
  __syncthreads();
  #pragma unroll
  for (int off = 1; off < 256; off <<= 1) {
    int t = (threadIdx.x >= off) ? s[threadIdx.x - off] : 0;
    __syncthreads();
    s[threadIdx.x] += t;
    __syncthreads();
  }
  if (threadIdx.x < nb) bsum[threadIdx.x] = s[threadIdx.x] - v;  // exclusive carry
}

__global__ __launch_bounds__(256) void k_scan3(const int* __restrict__ deg, int* __restrict__ offs,
                                               int* __restrict__ cursor, const int* __restrict__ bsum,
                                               int N, int E) {
  int i = blockIdx.x * 256 + threadIdx.x;
  if (i < N) {
    int o = offs[i] - deg[i] + bsum[blockIdx.x];  // exclusive
    offs[i] = o;
    cursor[i] = o;
  } else if (i == N) {
    offs[N] = E;
  }
}

__global__ void k_scatter(const int* __restrict__ dstv, int* __restrict__ cursor,
                          int* __restrict__ eids, int E) {
  int e = blockIdx.x * 256 + threadIdx.x;
  if (e < E) {
    int slot = atomicAdd(&cursor[dstv[e]], 1);
    eids[slot] = e;
  }
}

// ---------------- conv1 edge phase: hs[n] = sum_e relu(feat_e @ W1 + b1) ----------------
// feat = [x[dst](1), x[src](1), pos[src]-pos[dst](3)], W1 [5][128]
__global__ __launch_bounds__(64) void k_conv1(
    const float* __restrict__ x, const float* __restrict__ pos,
    const int* __restrict__ srcv, const int* __restrict__ offs, const int* __restrict__ eids,
    const float* __restrict__ w1, const float* __restrict__ b1, float* __restrict__ hs) {
  int n = blockIdx.x;
  int lane = threadIdx.x;
  __shared__ float sxs[64];
  __shared__ float sdp[3][64];
  int e0 = offs[n], e1 = offs[n + 1];
  float xi = x[n];
  float pix = pos[3 * n], piy = pos[3 * n + 1], piz = pos[3 * n + 2];
  float a1_0 = w1[HID + lane],     a1_1 = w1[HID + 64 + lane];
  float a2_0 = w1[2 * HID + lane], a2_1 = w1[2 * HID + 64 + lane];
  float a3_0 = w1[3 * HID + lane], a3_1 = w1[3 * HID + 64 + lane];
  float a4_0 = w1[4 * HID + lane], a4_1 = w1[4 * HID + 64 + lane];
  float c_0 = fmaf(xi, w1[lane],      b1[lane]);       // xi*W1[0][j] + b1[j] (const per node)
  float c_1 = fmaf(xi, w1[64 + lane], b1[64 + lane]);
  float acc0 = 0.f, acc1 = 0.f;
  for (int base = e0; base < e1; base += 64) {
    int cnt = min(64, e1 - base);
    if (lane < cnt) {
      int e = eids[base + lane];
      int s = srcv[e];
      sxs[lane] = x[s];
      sdp[0][lane] = pos[3 * s]     - pix;
      sdp[1][lane] = pos[3 * s + 1] - piy;
      sdp[2][lane] = pos[3 * s + 2] - piz;
    }
    __syncthreads();
    for (int k = 0; k < cnt; ++k) {
      float xj = sxs[k], d0 = sdp[0][k], d1 = sdp[1][k], d2 = sdp[2][k];
      float h0 = fmaf(xj, a1_0, fmaf(d0, a2_0, fmaf(d1, a3_0, fmaf(d2, a4_0, c_0))));
      float h1 = fmaf(xj, a1_1, fmaf(d0, a2_1, fmaf(d1, a3_1, fmaf(d2, a4_1, c_1))));
      acc0 += fmaxf(h0, 0.f);
      acc1 += fmaxf(h1, 0.f);
    }
    __syncthreads();
  }
  hs[(size_t)n * HID + lane]      = acc0;
  hs[(size_t)n * HID + 64 + lane] = acc1;
}

// ---------------- conv2 edge phase: hs[n] = sum_e relu(pd[n] + ps[src] + dpos @ Wc) ----------------
__global__ __launch_bounds__(64) void k_conv2(
    const float* __restrict__ pos,
    const int* __restrict__ srcv, const int* __restrict__ offs, const int* __restrict__ eids,
    const float* __restrict__ pd, const float* __restrict__ ps,
    const float* __restrict__ wc, float* __restrict__ hs) {
  int n = blockIdx.x;
  int lane = threadIdx.x;
  __shared__ int ssrc[64];
  __shared__ float sdp[3][64];
  int e0 = offs[n], e1 = offs[n + 1];
  float pix = pos[3 * n], piy = pos[3 * n + 1], piz = pos[3 * n + 2];
  float c0_0 = wc[lane],           c0_1 = wc[64 + lane];
  float c1_0 = wc[HID + lane],     c1_1 = wc[HID + 64 + lane];
  float c2_0 = wc[2 * HID + lane], c2_1 = wc[2 * HID + 64 + lane];
  float pd0 = pd[(size_t)n * HID + lane];
  float pd1 = pd[(size_t)n * HID + 64 + lane];
  float acc0 = 0.f, acc1 = 0.f;
  for (int base = e0; base < e1; base += 64) {
    int cnt = min(64, e1 - base);
    if (lane < cnt) {
      int e = eids[base + lane];
      int s = srcv[e];
      ssrc[lane] = s;
      sdp[0][lane] = pos[3 * s]     - pix;
      sdp[1][lane] = pos[3 * s + 1] - piy;
      sdp[2][lane] = pos[3 * s + 2] - piz;
    }
    __syncthreads();
    for (int k = 0; k < cnt; ++k) {
      int s = ssrc[k];
      float d0 = sdp[0][k], d1 = sdp[1][k], d2 = sdp[2][k];
      const float* psr = ps + (size_t)s * HID;
      float t0 = pd0 + psr[lane]      + fmaf(d0, c0_0, fmaf(d1, c1_0, d2 * c2_0));
      float t1 = pd1 + psr[64 + lane] + fmaf(d0, c0_1, fmaf(d1, c1_1, d2 * c2_1));
      acc0 += fmaxf(t0, 0.f);
      acc1 += fmaxf(t1, 0.f);
    }
    __syncthreads();
  }
  hs[(size_t)n * HID + lane]      = acc0;
  hs[(size_t)n * HID + 64 + lane] = acc1;
}

// ---------------- node GEMM: O = A[M x128] @ W[128 x128] (+epilogue) ----------------
// MODE 0: O1 = relu(A@W + deg*bias)   MODE 1: O1 = A@W + bias, O2 = A@WB   MODE 2: O1 = A@W
template <int MODE>
__global__ __launch_bounds__(256) void k_gemm(
    const float* __restrict__ A, const float* __restrict__ W, const float* __restrict__ WB,
    const float* __restrict__ bias, const int* __restrict__ deg,
    float* __restrict__ O1, float* __restrict__ O2, int M) {
  __shared__ float As[128][36];  // [i][r], stride 36 keeps float4 alignment, spreads banks
  int t = threadIdx.x;
  int n0 = blockIdx.x * 32;
  int j = t & 127, m = t >> 7;
  for (int idx = t; idx < 32 * 128; idx += 256) {
    int r = idx >> 7, i = idx & 127;
    int n = n0 + r;
    As[i][r] = (n < M) ? A[(size_t)n * 128 + i] : 0.f;
  }
  __syncthreads();
  float acc[16], accB[16];
  #pragma unroll
  for (int r = 0; r < 16; ++r) { acc[r] = 0.f; accB[r] = 0.f; }
  int rb = m * 16;
  for (int i = 0; i < 128; ++i) {
    float w = W[i * 128 + j];
    float wB = (MODE == 1) ? WB[i * 128 + j] : 0.f;
    const float4* ap = reinterpret_cast<const float4*>(&As[i][rb]);
    #pragma unroll
    for (int q = 0; q < 4; ++q) {
      float4 a = ap[q];
      acc[q * 4 + 0] = fmaf(a.x, w, acc[q * 4 + 0]);
      acc[q * 4 + 1] = fmaf(a.y, w, acc[q * 4 + 1]);
      acc[q * 4 + 2] = fmaf(a.z, w, acc[q * 4 + 2]);
      acc[q * 4 + 3] = fmaf(a.w, w, acc[q * 4 + 3]);
      if (MODE == 1) {
        accB[q * 4 + 0] = fmaf(a.x, wB, accB[q * 4 + 0]);
        accB[q * 4 + 1] = fmaf(a.y, wB, accB[q * 4 + 1]);
        accB[q * 4 + 2] = fmaf(a.z, wB, accB[q * 4 + 2]);
        accB[q * 4 + 3] = fmaf(a.w, wB, accB[q * 4 + 3]);
      }
    }
  }
  float bb = (MODE == 2) ? 0.f : bias[j];
  #pragma unroll
  for (int r = 0; r < 16; ++r) {
    int n = n0 + rb + r;
    if (n < M) {
      float v = acc[r];
      if (MODE == 0) v = fmaxf(fmaf((float)deg[n], bb, v), 0.f);
      if (MODE == 1) v = v + bb;
      O1[(size_t)n * 128 + j] = v;
      if (MODE == 1) O2[(size_t)n * 128 + j] = accB[r];
    }
  }
}

// ---------------- global add pool ----------------
__global__ void k_pool(const float* __restrict__ h2, const int* __restrict__ batch,
                       float* __restrict__ g, int N) {
  int idx = blockIdx.x * 256 + threadIdx.x;
  if (idx < N * 128) {
    int n = idx >> 7, j = idx & 127;
    atomicAdd(&g[(size_t)batch[n] * 128 + j], h2[idx]);
  }
}

// ---------------- batchnorm stats ----------------
__global__ __launch_bounds__(512) void k_bn(const float* __restrict__ z, float* __restrict__ mv, int G) {
  __shared__ float ss[4][128], sq[4][128];
  int j = threadIdx.x & 127, grp = threadIdx.x >> 7;
  float s = 0.f, q = 0.f;
  for (int r = grp; r < G; r += 4) {
    float v = z[(size_t)r * 128 + j];
    s += v;
    q = fmaf(v, v, q);
  }
  ss[grp][j] = s;
  sq[grp][j] = q;
  __syncthreads();
  if (grp == 0) {
    float S = ss[0][j] + ss[1][j] + ss[2][j] + ss[3][j];
    float Q = sq[0][j] + sq[1][j] + sq[2][j] + sq[3][j];
    float mean = S / (float)G;
    float var = Q / (float)G - mean * mean;
    mv[j] = mean;
    mv[128 + j] = rsqrtf(var + 1e-5f);
  }
}

// ---------------- BN-normalize + relu + final linear ----------------
__global__ __launch_bounds__(256) void k_final(
    const float* __restrict__ z, const float* __restrict__ mv,
    const float* __restrict__ gamma, const float* __restrict__ beta,
    const float* __restrict__ w2, const float* __restrict__ b2,
    float* __restrict__ out, int G) {
  int wid = threadIdx.x >> 6, lane = threadIdx.x & 63;
  int r = blockIdx.x * 4 + wid;
  if (r >= G) return;
  float acc = 0.f;
  #pragma unroll
  for (int h = 0; h < 2; ++h) {
    int jj = lane + h * 64;
    float v = z[(size_t)r * 128 + jj];
    float zn = fmaf((v - mv[jj]) * mv[128 + jj], gamma[jj], beta[jj]);
    acc = fmaf(fmaxf(zn, 0.f), w2[jj], acc);
  }
  #pragma unroll
  for (int off = 32; off; off >>= 1) acc += __shfl_down(acc, off);
  if (lane == 0) out[r] = acc + b2[0];
}

extern "C" void kernel_launch(void* const* d_in, const int* in_sizes, int n_in,
                              void* d_out, int out_size, void* d_ws, size_t ws_size,
                              hipStream_t stream) {
  const float* x     = (const float*)d_in[0];
  const float* pos   = (const float*)d_in[1];
  const int*   eidx  = (const int*)d_in[2];
  const int*   batch = (const int*)d_in[3];
  const float* c1w1  = (const float*)d_in[4];
  const float* c1b1  = (const float*)d_in[5];
  const float* c1w2  = (const float*)d_in[6];
  const float* c1b2  = (const float*)d_in[7];
  const float* c2w1  = (const float*)d_in[8];
  const float* c2b1  = (const float*)d_in[9];
  const float* c2w2  = (const float*)d_in[10];
  const float* c2b2  = (const float*)d_in[11];
  const float* pw1   = (const float*)d_in[12];
  const float* gamma = (const float*)d_in[13];
  const float* beta  = (const float*)d_in[14];
  const float* pw2   = (const float*)d_in[15];
  const float* pb2   = (const float*)d_in[16];
  (void)n_in; (void)ws_size;

  const int N = in_sizes[0];        // 50000 (x is [N,1])
  const int E = in_sizes[2] / 2;    // 800000
  const int G = out_size;           // 512
  const int* srcv = eidx;
  const int* dstv = eidx + E;

  char* w = (char*)d_ws;
  size_t o = 0;
  auto carve = [&](size_t bytes) { void* p = w + o; o = (o + bytes + 255) & ~(size_t)255; return p; };
  int Npad = ((N + 255) / 256) * 256;
  int* deg    = (int*)carve((size_t)Npad * 4);
  int* offs   = (int*)carve((size_t)(Npad + 256) * 4);
  int* cursor = (int*)carve((size_t)Npad * 4);
  int* bsum   = (int*)carve(256 * 4);
  int* eids   = (int*)carve((size_t)E * 4);
  float* bufA = (float*)carve((size_t)N * HID * 4);
  float* bufB = (float*)carve((size_t)N * HID * 4);
  float* bufC = (float*)carve((size_t)N * HID * 4);
  float* g    = (float*)carve((size_t)G * HID * 4);
  float* z    = (float*)carve((size_t)G * HID * 4);
  float* mv   = (float*)carve(256 * 4);

  int nbN = (N + 255) / 256;
  int nbE = (E + 255) / 256;

  hipMemsetAsync(deg, 0, (size_t)Npad * 4, stream);
  hipMemsetAsync(g, 0, (size_t)G * HID * 4, stream);

  // CSR build
  k_count<<<nbE, 256, 0, stream>>>(dstv, deg, E);
  k_scan1<<<nbN, 256, 0, stream>>>(deg, offs, bsum, N);
  k_scan2<<<1, 256, 0, stream>>>(bsum, nbN);
  k_scan3<<<(N + 256) / 256, 256, 0, stream>>>(deg, offs, cursor, bsum, N, E);
  k_scatter<<<nbE, 256, 0, stream>>>(dstv, cursor, eids, E);

  int gb = (N + 31) / 32;
  // conv1
  k_conv1<<<N, 64, 0, stream>>>(x, pos, srcv, offs, eids, c1w1, c1b1, bufA);
  k_gemm<0><<<gb, 256, 0, stream>>>(bufA, c1w2, nullptr, c1b2, deg, bufB, nullptr, N);  // h1 = relu(hs@W2 + deg*b2)
  // conv2 precompute: pd = h1@W1a + b1, ps = h1@W1b
  k_gemm<1><<<gb, 256, 0, stream>>>(bufB, c2w1, c2w1 + 128 * HID, c2b1, nullptr, bufC, bufA, N);
  k_conv2<<<N, 64, 0, stream>>>(pos, srcv, offs, eids, bufC, bufA, c2w1 + 256 * HID, bufB);
  k_gemm<0><<<gb, 256, 0, stream>>>(bufB, c2w2, nullptr, c2b2, deg, bufC, nullptr, N);  // h2
  // pool
  k_pool<<<(N * HID + 255) / 256, 256, 0, stream>>>(bufC, batch, g, N);
  // predictor
  k_gemm<2><<<(G + 31) / 32, 256, 0, stream>>>(g, pw1, nullptr, nullptr, nullptr, z, nullptr, G);
  k_bn<<<1, 512, 0, stream>>>(z, mv, G);
  k_final<<<(G + 3) / 4, 256, 0, stream>>>(z, mv, gamma, beta, pw2, pb2, (float*)d_out, G);
}